// Round 1
// baseline (5859.479 us; speedup 1.0000x reference)
//
#include <hip/hip_runtime.h>
#include <hip/hip_bf16.h>
#include <cstdint>

#define D_DIM 2048
#define F_DIM 1024
#define E_NUM 64
#define K_TOP 8
#define CAP   1024

#define BM 64
#define BN 64
#define BK 16

__device__ __forceinline__ float bf16_to_f(uint16_t u) {
    union { uint32_t u; float f; } v; v.u = ((uint32_t)u) << 16; return v.f;
}
__device__ __forceinline__ uint16_t f_to_bf16(float f) {
    union { float f; uint32_t u; } v; v.f = f;
    uint32_t r = v.u + 0x7FFF + ((v.u >> 16) & 1);
    return (uint16_t)(r >> 16);
}

// ---------------- Router: logits, softmax, top-8 ----------------
__global__ __launch_bounds__(64) void router_k(const float* __restrict__ x,
        const float* __restrict__ gw, int* __restrict__ topi,
        float* __restrict__ topw) {
    int t = blockIdx.x;
    int tid = threadIdx.x;
    __shared__ float xs[D_DIM];
    __shared__ float lg[E_NUM];
    const float* xr = x + (size_t)t * D_DIM;
    for (int d = tid; d < D_DIM; d += 64) xs[d] = xr[d];
    __syncthreads();
    const float* w = gw + (size_t)tid * D_DIM;
    float acc = 0.f;
    #pragma unroll 8
    for (int d = 0; d < D_DIM; ++d) acc = fmaf(xs[d], w[d], acc);
    lg[tid] = acc;
    __syncthreads();
    if (tid == 0) {
        float mx = -INFINITY;
        for (int e = 0; e < E_NUM; ++e) mx = fmaxf(mx, lg[e]);
        float se = 0.f;
        for (int e = 0; e < E_NUM; ++e) se += expf(lg[e] - mx);
        float inv = 1.f / se;
        uint64_t used = 0;
        for (int k = 0; k < K_TOP; ++k) {
            int bi = 0; float bv = -INFINITY;
            for (int e = 0; e < E_NUM; ++e) {
                if (!((used >> e) & 1) && lg[e] > bv) { bv = lg[e]; bi = e; }
            }
            used |= 1ull << bi;
            topi[t * K_TOP + k] = bi;
            topw[t * K_TOP + k] = expf(bv - mx) * inv;
        }
    }
}

// ---------------- Slot assignment via atomics ----------------
__global__ void assign_k(const int* __restrict__ topi, const float* __restrict__ topw,
        int* __restrict__ cnt, int* __restrict__ rowtok, float* __restrict__ aw, int T) {
    int t = blockIdx.x * blockDim.x + threadIdx.x;
    if (t >= T) return;
    for (int k = 0; k < K_TOP; ++k) {
        int e = topi[t * K_TOP + k];
        int pos = atomicAdd(&cnt[e], 1);
        if (pos < CAP) {
            rowtok[e * CAP + pos] = t;
            aw[e * CAP + pos] = topw[t * K_TOP + k];
        }
    }
}

// ---------------- Gate+Up GEMM: h = silu(Xe Wg) * (Xe Wu), bf16 out -------
__global__ __launch_bounds__(256) void gateup_k(const float* __restrict__ x,
        const float* __restrict__ wg, const float* __restrict__ wu,
        const int* __restrict__ cnt, const int* __restrict__ rowtok,
        uint16_t* __restrict__ h) {
    int ftile = blockIdx.x;               // 0..F/BN-1
    int eyt = blockIdx.y;                 // e*(CAP/BM) + rowtile
    int e = eyt >> 4;
    int m0 = (eyt & 15) * BM;
    int ne = min(cnt[e], CAP);
    int nr = ne - m0;
    if (nr <= 0) return;
    if (nr > BM) nr = BM;
    int tid = threadIdx.x;
    int tx = tid & 15, ty = tid >> 4;

    __shared__ float As[BK][BM];
    __shared__ float Bg[BK][BN];
    __shared__ float Bu[BK][BN];

    int lrow = tid >> 2;                  // 0..63
    int lkq  = (tid & 3) * 4;             // 0,4,8,12
    int ltok = rowtok[e * CAP + m0 + min(lrow, nr - 1)];
    const float* aptr = x + (size_t)ltok * D_DIM + lkq;

    int bk = tid >> 4;                    // 0..15
    int bf = (tid & 15) * 4;
    size_t wbase = (size_t)e * D_DIM * F_DIM + (size_t)bk * F_DIM + ftile * BN + bf;
    const float* gptr = wg + wbase;
    const float* uptr = wu + wbase;

    float accg[4][4] = {{0.f}};
    float accu[4][4] = {{0.f}};

    for (int k0 = 0; k0 < D_DIM; k0 += BK) {
        float4 av = *(const float4*)(aptr + k0);
        float4 gv = *(const float4*)(gptr + (size_t)k0 * F_DIM);
        float4 uv = *(const float4*)(uptr + (size_t)k0 * F_DIM);
        __syncthreads();
        As[lkq + 0][lrow] = av.x; As[lkq + 1][lrow] = av.y;
        As[lkq + 2][lrow] = av.z; As[lkq + 3][lrow] = av.w;
        *(float4*)&Bg[bk][bf] = gv;
        *(float4*)&Bu[bk][bf] = uv;
        __syncthreads();
        #pragma unroll
        for (int k = 0; k < BK; ++k) {
            float a[4], g[4], u[4];
            #pragma unroll
            for (int i = 0; i < 4; ++i) a[i] = As[k][ty * 4 + i];
            #pragma unroll
            for (int j = 0; j < 4; ++j) { g[j] = Bg[k][tx * 4 + j]; u[j] = Bu[k][tx * 4 + j]; }
            #pragma unroll
            for (int i = 0; i < 4; ++i)
                #pragma unroll
                for (int j = 0; j < 4; ++j) {
                    accg[i][j] = fmaf(a[i], g[j], accg[i][j]);
                    accu[i][j] = fmaf(a[i], u[j], accu[i][j]);
                }
        }
    }
    #pragma unroll
    for (int i = 0; i < 4; ++i) {
        int row = ty * 4 + i;
        if (row < nr) {
            size_t hbase = ((size_t)(e * CAP + m0 + row)) * F_DIM + ftile * BN + tx * 4;
            #pragma unroll
            for (int j = 0; j < 4; ++j) {
                float gvv = accg[i][j], uvv = accu[i][j];
                float hv = gvv / (1.f + expf(-gvv)) * uvv;
                h[hbase + j] = f_to_bf16(hv);
            }
        }
    }
}

// ---------------- Down GEMM + weighted atomic combine ----------------
__global__ __launch_bounds__(256) void down_k(const uint16_t* __restrict__ h,
        const float* __restrict__ wd, const int* __restrict__ cnt,
        const int* __restrict__ rowtok, const float* __restrict__ aw,
        float* __restrict__ out) {
    int ftile = blockIdx.x;               // 0..D/BN-1
    int eyt = blockIdx.y;
    int e = eyt >> 4;
    int m0 = (eyt & 15) * BM;
    int ne = min(cnt[e], CAP);
    int nr = ne - m0;
    if (nr <= 0) return;
    if (nr > BM) nr = BM;
    int tid = threadIdx.x;
    int tx = tid & 15, ty = tid >> 4;

    __shared__ float As[BK][BM];
    __shared__ float Bs[BK][BN];

    int lrow = tid >> 2;
    int lkq  = (tid & 3) * 4;
    int arow = m0 + min(lrow, nr - 1);
    const uint16_t* aptr = h + (size_t)(e * CAP + arow) * F_DIM + lkq;

    int bk = tid >> 4;
    int bf = (tid & 15) * 4;
    const float* bptr = wd + (size_t)e * F_DIM * D_DIM + (size_t)bk * D_DIM + ftile * BN + bf;

    float acc[4][4] = {{0.f}};

    for (int k0 = 0; k0 < F_DIM; k0 += BK) {
        ushort4 av = *(const ushort4*)(aptr + k0);
        float4 bv = *(const float4*)(bptr + (size_t)k0 * D_DIM);
        __syncthreads();
        As[lkq + 0][lrow] = bf16_to_f(av.x);
        As[lkq + 1][lrow] = bf16_to_f(av.y);
        As[lkq + 2][lrow] = bf16_to_f(av.z);
        As[lkq + 3][lrow] = bf16_to_f(av.w);
        *(float4*)&Bs[bk][bf] = bv;
        __syncthreads();
        #pragma unroll
        for (int k = 0; k < BK; ++k) {
            float a[4], b[4];
            #pragma unroll
            for (int i = 0; i < 4; ++i) a[i] = As[k][ty * 4 + i];
            #pragma unroll
            for (int j = 0; j < 4; ++j) b[j] = Bs[k][tx * 4 + j];
            #pragma unroll
            for (int i = 0; i < 4; ++i)
                #pragma unroll
                for (int j = 0; j < 4; ++j)
                    acc[i][j] = fmaf(a[i], b[j], acc[i][j]);
        }
    }
    #pragma unroll
    for (int i = 0; i < 4; ++i) {
        int row = ty * 4 + i;
        if (row < nr) {
            int slot = e * CAP + m0 + row;
            int tok = rowtok[slot];
            float wgt = aw[slot];
            float* orow = out + (size_t)tok * D_DIM + ftile * BN + tx * 4;
            #pragma unroll
            for (int j = 0; j < 4; ++j)
                atomicAdd(&orow[j], acc[i][j] * wgt);
        }
    }
}

extern "C" void kernel_launch(void* const* d_in, const int* in_sizes, int n_in,
                              void* d_out, int out_size, void* d_ws, size_t ws_size,
                              hipStream_t stream) {
    const float* x  = (const float*)d_in[0];
    const float* gw = (const float*)d_in[1];
    const float* wg = (const float*)d_in[2];
    const float* wu = (const float*)d_in[3];
    const float* wd = (const float*)d_in[4];
    float* out = (float*)d_out;
    int T = in_sizes[0] / D_DIM;   // B*S = 4096

    char* ws = (char*)d_ws;
    size_t off = 0;
    auto alloc = [&](size_t bytes) -> void* {
        void* p = ws + off;
        off = (off + bytes + 255) & ~(size_t)255;
        return p;
    };
    int*      cnt    = (int*)     alloc(E_NUM * sizeof(int));
    int*      topi   = (int*)     alloc((size_t)T * K_TOP * sizeof(int));
    float*    topw   = (float*)   alloc((size_t)T * K_TOP * sizeof(float));
    int*      rowtok = (int*)     alloc((size_t)E_NUM * CAP * sizeof(int));
    float*    aw     = (float*)   alloc((size_t)E_NUM * CAP * sizeof(float));
    uint16_t* h      = (uint16_t*)alloc((size_t)E_NUM * CAP * F_DIM * sizeof(uint16_t));

    hipMemsetAsync(cnt, 0, E_NUM * sizeof(int), stream);
    hipMemsetAsync(out, 0, (size_t)out_size * sizeof(float), stream);

    router_k<<<T, 64, 0, stream>>>(x, gw, topi, topw);
    assign_k<<<(T + 255) / 256, 256, 0, stream>>>(topi, topw, cnt, rowtok, aw, T);
    gateup_k<<<dim3(F_DIM / BN, E_NUM * (CAP / BM)), 256, 0, stream>>>(x, wg, wu, cnt, rowtok, h);
    down_k<<<dim3(D_DIM / BN, E_NUM * (CAP / BM)), 256, 0, stream>>>(h, wd, cnt, rowtok, aw, out);
}

// Round 2
// 2853.906 us; speedup vs baseline: 2.0531x; 2.0531x over previous
//
#include <hip/hip_runtime.h>
#include <hip/hip_bf16.h>
#include <cstdint>

#define D_DIM 2048
#define F_DIM 1024
#define E_NUM 64
#define K_TOP 8
#define CAP   1024

typedef __attribute__((ext_vector_type(8))) short short8;
typedef __attribute__((ext_vector_type(4))) float f32x4;

__device__ __forceinline__ uint16_t f_to_bf16(float f) {
    union { float f; uint32_t u; } v; v.f = f;
    uint32_t r = v.u + 0x7FFF + ((v.u >> 16) & 1);
    return (uint16_t)(r >> 16);
}
__device__ __forceinline__ uint32_t pack2(float a, float b) {
    return (uint32_t)f_to_bf16(a) | ((uint32_t)f_to_bf16(b) << 16);
}

// ---------------- x -> bf16 ----------------
__global__ __launch_bounds__(256) void cvtx_k(const float* __restrict__ x,
        uint16_t* __restrict__ xb, int n8) {
    int i = blockIdx.x * 256 + threadIdx.x;
    if (i >= n8) return;
    const float4* p = (const float4*)x + (size_t)i * 2;
    float4 a = p[0], b = p[1];
    uint4 o;
    o.x = pack2(a.x, a.y); o.y = pack2(a.z, a.w);
    o.z = pack2(b.x, b.y); o.w = pack2(b.z, b.w);
    ((uint4*)xb)[i] = o;
}

// ---------------- Router: logits, softmax, top-8 ----------------
__global__ __launch_bounds__(64) void router_k(const float* __restrict__ x,
        const float* __restrict__ gw, int* __restrict__ topi,
        float* __restrict__ topw) {
    int t = blockIdx.x;
    int tid = threadIdx.x;
    __shared__ float xs[D_DIM];
    __shared__ float lg[E_NUM];
    const float* xr = x + (size_t)t * D_DIM;
    for (int d = tid; d < D_DIM; d += 64) xs[d] = xr[d];
    __syncthreads();
    const float* w = gw + (size_t)tid * D_DIM;
    float acc = 0.f;
    #pragma unroll 8
    for (int d = 0; d < D_DIM; ++d) acc = fmaf(xs[d], w[d], acc);
    lg[tid] = acc;
    __syncthreads();
    if (tid == 0) {
        float mx = -INFINITY;
        for (int e = 0; e < E_NUM; ++e) mx = fmaxf(mx, lg[e]);
        float se = 0.f;
        for (int e = 0; e < E_NUM; ++e) se += expf(lg[e] - mx);
        float inv = 1.f / se;
        uint64_t used = 0;
        for (int k = 0; k < K_TOP; ++k) {
            int bi = 0; float bv = -INFINITY;
            for (int e = 0; e < E_NUM; ++e) {
                if (!((used >> e) & 1) && lg[e] > bv) { bv = lg[e]; bi = e; }
            }
            used |= 1ull << bi;
            topi[t * K_TOP + k] = bi;
            topw[t * K_TOP + k] = expf(bv - mx) * inv;
        }
    }
}

// ---------------- Slot assignment via atomics ----------------
__global__ void assign_k(const int* __restrict__ topi, const float* __restrict__ topw,
        int* __restrict__ cnt, int* __restrict__ rowtok, float* __restrict__ aw, int T) {
    int t = blockIdx.x * blockDim.x + threadIdx.x;
    if (t >= T) return;
    for (int k = 0; k < K_TOP; ++k) {
        int e = topi[t * K_TOP + k];
        int pos = atomicAdd(&cnt[e], 1);
        if (pos < CAP) {
            rowtok[e * CAP + pos] = t;
            aw[e * CAP + pos] = topw[t * K_TOP + k];
        }
    }
}

// ---------------- Gate+Up MFMA GEMM: h = silu(Xe Wg) * (Xe Wu) ----------
// block: 128 rows x 64 f-cols, both matrices. 4 waves (2x2), wave = 64x32.
__global__ __launch_bounds__(256, 2) void gateup_k(const uint16_t* __restrict__ xb,
        const float* __restrict__ wg, const float* __restrict__ wu,
        const int* __restrict__ cnt, const int* __restrict__ rowtok,
        uint16_t* __restrict__ h) {
    int mtile = blockIdx.x;
    int e = blockIdx.y >> 4;
    int ftile = blockIdx.y & 15;
    int m0 = mtile * 128;
    int ne = min(cnt[e], CAP);
    int nr = ne - m0;
    if (nr <= 0) return;
    if (nr > 128) nr = 128;
    int slot0 = e * CAP + m0;

    __shared__ __align__(16) unsigned char Asm[128 * 80];
    __shared__ __align__(16) unsigned char Bgm[64 * 80];
    __shared__ __align__(16) unsigned char Bum[64 * 80];

    int tid = threadIdx.x;
    int l = tid & 63, wid = tid >> 6;
    int wr = wid >> 1, wc = wid & 1;
    int ln = l & 15, lg2 = l >> 4;

    // A staging: row ar, k-chunks aq0 and aq0+2 (8 bf16 = 16B each)
    int ar = tid & 127, aq0 = tid >> 7;
    int tok = rowtok[slot0 + min(ar, nr - 1)];
    const uint4* ap0 = (const uint4*)(xb + (size_t)tok * D_DIM + aq0 * 8);
    const uint4* ap1 = (const uint4*)(xb + (size_t)tok * D_DIM + (aq0 + 2) * 8);
    uint4* asw0 = (uint4*)(Asm + ar * 80 + aq0 * 16);
    uint4* asw1 = (uint4*)(Asm + ar * 80 + (aq0 + 2) * 16);

    // B staging: col bf, k-chunk bq (8 strided fp32 -> 8 bf16)
    int bfc = tid & 63, bq = tid >> 6;
    size_t wbase = (size_t)e * D_DIM * F_DIM + (size_t)(bq * 8) * F_DIM
                 + (size_t)ftile * 64 + bfc;
    const float* gp = wg + wbase;
    const float* up = wu + wbase;
    uint4* bgw = (uint4*)(Bgm + bfc * 80 + bq * 16);
    uint4* buw = (uint4*)(Bum + bfc * 80 + bq * 16);

    f32x4 accg[4][2], accu[4][2];
    #pragma unroll
    for (int mi = 0; mi < 4; ++mi)
        #pragma unroll
        for (int ni = 0; ni < 2; ++ni) {
            accg[mi][ni] = (f32x4){0.f, 0.f, 0.f, 0.f};
            accu[mi][ni] = (f32x4){0.f, 0.f, 0.f, 0.f};
        }

    for (int k0 = 0; k0 < D_DIM; k0 += 32) {
        uint4 av0 = ap0[k0 >> 3];
        uint4 av1 = ap1[k0 >> 3];
        float gv[8], uv[8];
        #pragma unroll
        for (int j = 0; j < 8; ++j) {
            gv[j] = gp[(size_t)(k0 + j) * F_DIM];
            uv[j] = up[(size_t)(k0 + j) * F_DIM];
        }
        uint4 g4, u4;
        g4.x = pack2(gv[0], gv[1]); g4.y = pack2(gv[2], gv[3]);
        g4.z = pack2(gv[4], gv[5]); g4.w = pack2(gv[6], gv[7]);
        u4.x = pack2(uv[0], uv[1]); u4.y = pack2(uv[2], uv[3]);
        u4.z = pack2(uv[4], uv[5]); u4.w = pack2(uv[6], uv[7]);
        __syncthreads();
        *asw0 = av0; *asw1 = av1;
        *bgw = g4; *buw = u4;
        __syncthreads();
        short8 af[4];
        #pragma unroll
        for (int mi = 0; mi < 4; ++mi)
            af[mi] = *(const short8*)(Asm + (wr * 64 + mi * 16 + ln) * 80 + lg2 * 16);
        short8 bgf[2], buf_[2];
        #pragma unroll
        for (int ni = 0; ni < 2; ++ni) {
            bgf[ni]  = *(const short8*)(Bgm + (wc * 32 + ni * 16 + ln) * 80 + lg2 * 16);
            buf_[ni] = *(const short8*)(Bum + (wc * 32 + ni * 16 + ln) * 80 + lg2 * 16);
        }
        #pragma unroll
        for (int mi = 0; mi < 4; ++mi)
            #pragma unroll
            for (int ni = 0; ni < 2; ++ni) {
                accg[mi][ni] = __builtin_amdgcn_mfma_f32_16x16x32_bf16(af[mi], bgf[ni],  accg[mi][ni], 0, 0, 0);
                accu[mi][ni] = __builtin_amdgcn_mfma_f32_16x16x32_bf16(af[mi], buf_[ni], accu[mi][ni], 0, 0, 0);
            }
    }

    // epilogue: h = silu(g)*u, bf16
    #pragma unroll
    for (int mi = 0; mi < 4; ++mi) {
        int rbase = wr * 64 + mi * 16 + lg2 * 4;
        #pragma unroll
        for (int j = 0; j < 4; ++j) {
            int row = rbase + j;
            if (row < nr) {
                size_t hb = (size_t)(slot0 + row) * F_DIM + (size_t)ftile * 64 + wc * 32 + ln;
                #pragma unroll
                for (int ni = 0; ni < 2; ++ni) {
                    float g = accg[mi][ni][j], u = accu[mi][ni][j];
                    float hv = g / (1.f + __expf(-g)) * u;
                    h[hb + ni * 16] = f_to_bf16(hv);
                }
            }
        }
    }
}

// ---------------- Down MFMA GEMM + weighted atomic combine ----------------
__global__ __launch_bounds__(256, 2) void down_k(const uint16_t* __restrict__ h,
        const float* __restrict__ wd, const int* __restrict__ cnt,
        const int* __restrict__ rowtok, const float* __restrict__ aw,
        float* __restrict__ out) {
    int mtile = blockIdx.x;
    int e = blockIdx.y >> 5;
    int ftile = blockIdx.y & 31;
    int m0 = mtile * 128;
    int ne = min(cnt[e], CAP);
    int nr = ne - m0;
    if (nr <= 0) return;
    if (nr > 128) nr = 128;
    int slot0 = e * CAP + m0;

    __shared__ __align__(16) unsigned char Asm[128 * 80];
    __shared__ __align__(16) unsigned char Bsm[64 * 80];

    int tid = threadIdx.x;
    int l = tid & 63, wid = tid >> 6;
    int wr = wid >> 1, wc = wid & 1;
    int ln = l & 15, lg2 = l >> 4;

    int ar = tid & 127, aq0 = tid >> 7;
    const uint4* ap0 = (const uint4*)(h + (size_t)(slot0 + ar) * F_DIM + aq0 * 8);
    const uint4* ap1 = (const uint4*)(h + (size_t)(slot0 + ar) * F_DIM + (aq0 + 2) * 8);
    uint4* asw0 = (uint4*)(Asm + ar * 80 + aq0 * 16);
    uint4* asw1 = (uint4*)(Asm + ar * 80 + (aq0 + 2) * 16);

    int bfc = tid & 63, bq = tid >> 6;
    const float* bp = wd + (size_t)e * F_DIM * D_DIM + (size_t)(bq * 8) * D_DIM
                    + (size_t)ftile * 64 + bfc;
    uint4* bsw = (uint4*)(Bsm + bfc * 80 + bq * 16);

    f32x4 acc[4][2];
    #pragma unroll
    for (int mi = 0; mi < 4; ++mi)
        #pragma unroll
        for (int ni = 0; ni < 2; ++ni)
            acc[mi][ni] = (f32x4){0.f, 0.f, 0.f, 0.f};

    for (int k0 = 0; k0 < F_DIM; k0 += 32) {
        uint4 av0 = ap0[k0 >> 3];
        uint4 av1 = ap1[k0 >> 3];
        float bv[8];
        #pragma unroll
        for (int j = 0; j < 8; ++j)
            bv[j] = bp[(size_t)(k0 + j) * D_DIM];
        uint4 b4;
        b4.x = pack2(bv[0], bv[1]); b4.y = pack2(bv[2], bv[3]);
        b4.z = pack2(bv[4], bv[5]); b4.w = pack2(bv[6], bv[7]);
        __syncthreads();
        *asw0 = av0; *asw1 = av1;
        *bsw = b4;
        __syncthreads();
        short8 af[4];
        #pragma unroll
        for (int mi = 0; mi < 4; ++mi)
            af[mi] = *(const short8*)(Asm + (wr * 64 + mi * 16 + ln) * 80 + lg2 * 16);
        short8 bf2[2];
        #pragma unroll
        for (int ni = 0; ni < 2; ++ni)
            bf2[ni] = *(const short8*)(Bsm + (wc * 32 + ni * 16 + ln) * 80 + lg2 * 16);
        #pragma unroll
        for (int mi = 0; mi < 4; ++mi)
            #pragma unroll
            for (int ni = 0; ni < 2; ++ni)
                acc[mi][ni] = __builtin_amdgcn_mfma_f32_16x16x32_bf16(af[mi], bf2[ni], acc[mi][ni], 0, 0, 0);
    }

    #pragma unroll
    for (int mi = 0; mi < 4; ++mi) {
        int rbase = wr * 64 + mi * 16 + lg2 * 4;
        #pragma unroll
        for (int j = 0; j < 4; ++j) {
            int row = rbase + j;
            if (row < nr) {
                int slot = slot0 + row;
                int tok = rowtok[slot];
                float wgt = aw[slot];
                float* orow = out + (size_t)tok * D_DIM + (size_t)ftile * 64 + wc * 32 + ln;
                #pragma unroll
                for (int ni = 0; ni < 2; ++ni)
                    atomicAdd(&orow[ni * 16], acc[mi][ni][j] * wgt);
            }
        }
    }
}

extern "C" void kernel_launch(void* const* d_in, const int* in_sizes, int n_in,
                              void* d_out, int out_size, void* d_ws, size_t ws_size,
                              hipStream_t stream) {
    const float* x  = (const float*)d_in[0];
    const float* gw = (const float*)d_in[1];
    const float* wg = (const float*)d_in[2];
    const float* wu = (const float*)d_in[3];
    const float* wd = (const float*)d_in[4];
    float* out = (float*)d_out;
    int T = in_sizes[0] / D_DIM;

    char* ws = (char*)d_ws;
    size_t off = 0;
    auto alloc = [&](size_t bytes) -> void* {
        void* p = ws + off;
        off = (off + bytes + 255) & ~(size_t)255;
        return p;
    };
    int*      cnt    = (int*)     alloc(E_NUM * sizeof(int));
    int*      topi   = (int*)     alloc((size_t)T * K_TOP * sizeof(int));
    float*    topw   = (float*)   alloc((size_t)T * K_TOP * sizeof(float));
    int*      rowtok = (int*)     alloc((size_t)E_NUM * CAP * sizeof(int));
    float*    aw     = (float*)   alloc((size_t)E_NUM * CAP * sizeof(float));
    uint16_t* xb     = (uint16_t*)alloc((size_t)T * D_DIM * sizeof(uint16_t));
    uint16_t* h      = (uint16_t*)alloc((size_t)E_NUM * CAP * F_DIM * sizeof(uint16_t));

    hipMemsetAsync(cnt, 0, E_NUM * sizeof(int), stream);
    hipMemsetAsync(out, 0, (size_t)out_size * sizeof(float), stream);

    int n8 = T * D_DIM / 8;
    cvtx_k<<<(n8 + 255) / 256, 256, 0, stream>>>(x, xb, n8);
    router_k<<<T, 64, 0, stream>>>(x, gw, topi, topw);
    assign_k<<<(T + 255) / 256, 256, 0, stream>>>(topi, topw, cnt, rowtok, aw, T);
    gateup_k<<<dim3(CAP / 128, E_NUM * (F_DIM / 64)), 256, 0, stream>>>(xb, wg, wu, cnt, rowtok, h);
    down_k<<<dim3(CAP / 128, E_NUM * (D_DIM / 64)), 256, 0, stream>>>(h, wd, cnt, rowtok, aw, out);
}

// Round 3
// 1896.340 us; speedup vs baseline: 3.0899x; 1.5050x over previous
//
#include <hip/hip_runtime.h>
#include <hip/hip_bf16.h>
#include <cstdint>

#define D_DIM 2048
#define F_DIM 1024
#define E_NUM 64
#define K_TOP 8
#define CAP   1024
#define PITCH 144   // LDS row pitch bytes (64 bf16 = 128B + 16 pad): frag reads 2-way (free)

typedef __attribute__((ext_vector_type(8))) short short8;
typedef __attribute__((ext_vector_type(4))) float f32x4;

__device__ __forceinline__ uint16_t f_to_bf16(float f) {
    union { float f; uint32_t u; } v; v.f = f;
    uint32_t r = v.u + 0x7FFF + ((v.u >> 16) & 1);
    return (uint16_t)(r >> 16);
}
__device__ __forceinline__ uint32_t pack2(float a, float b) {
    __hip_bfloat162 t = __float22bfloat162_rn(make_float2(a, b));
    return *reinterpret_cast<uint32_t*>(&t);
}

// ---------------- x -> bf16 ----------------
__global__ __launch_bounds__(256) void cvtx_k(const float* __restrict__ x,
        uint16_t* __restrict__ xb, int n8) {
    int i = blockIdx.x * 256 + threadIdx.x;
    if (i >= n8) return;
    const float4* p = (const float4*)x + (size_t)i * 2;
    float4 a = p[0], b = p[1];
    uint4 o;
    o.x = pack2(a.x, a.y); o.y = pack2(a.z, a.w);
    o.z = pack2(b.x, b.y); o.w = pack2(b.z, b.w);
    ((uint4*)xb)[i] = o;
}

// ---------------- Router ----------------
__global__ __launch_bounds__(64) void router_k(const float* __restrict__ x,
        const float* __restrict__ gw, int* __restrict__ topi,
        float* __restrict__ topw) {
    int t = blockIdx.x;
    int tid = threadIdx.x;
    __shared__ float xs[D_DIM];
    __shared__ float lgs[E_NUM];
    const float* xr = x + (size_t)t * D_DIM;
    for (int d = tid; d < D_DIM; d += 64) xs[d] = xr[d];
    __syncthreads();
    const float* w = gw + (size_t)tid * D_DIM;
    float acc = 0.f;
    #pragma unroll 8
    for (int d = 0; d < D_DIM; ++d) acc = fmaf(xs[d], w[d], acc);
    lgs[tid] = acc;
    __syncthreads();
    if (tid == 0) {
        float mx = -INFINITY;
        for (int e = 0; e < E_NUM; ++e) mx = fmaxf(mx, lgs[e]);
        float se = 0.f;
        for (int e = 0; e < E_NUM; ++e) se += expf(lgs[e] - mx);
        float inv = 1.f / se;
        uint64_t used = 0;
        for (int k = 0; k < K_TOP; ++k) {
            int bi = 0; float bv = -INFINITY;
            for (int e = 0; e < E_NUM; ++e) {
                if (!((used >> e) & 1) && lgs[e] > bv) { bv = lgs[e]; bi = e; }
            }
            used |= 1ull << bi;
            topi[t * K_TOP + k] = bi;
            topw[t * K_TOP + k] = expf(bv - mx) * inv;
        }
    }
}

// ---------------- Slot assignment ----------------
__global__ void assign_k(const int* __restrict__ topi, const float* __restrict__ topw,
        int* __restrict__ cnt, int* __restrict__ rowtok, float* __restrict__ aw, int T) {
    int t = blockIdx.x * blockDim.x + threadIdx.x;
    if (t >= T) return;
    for (int k = 0; k < K_TOP; ++k) {
        int e = topi[t * K_TOP + k];
        int pos = atomicAdd(&cnt[e], 1);
        if (pos < CAP) {
            rowtok[e * CAP + pos] = t;
            aw[e * CAP + pos] = topw[t * K_TOP + k];
        }
    }
}

// ------- Gate+Up GEMM: 128m x 128f tile, BK=64, 512 thr, reg-dbuf pipeline -------
__global__ __launch_bounds__(512, 2) void gateup_k(const uint16_t* __restrict__ xb,
        const float* __restrict__ wg, const float* __restrict__ wu,
        const int* __restrict__ cnt, const int* __restrict__ rowtok,
        uint16_t* __restrict__ h) {
    // XCD swizzle: xcd = ftile-strip % 8; m-tiles consecutive within XCD
    int flat = blockIdx.x;
    int xcd = flat & 7;
    int idx = flat >> 3;
    int m = idx & 7;
    int sloc = idx >> 3;
    int strip = sloc * 8 + xcd;          // 0..511 = e*8 + f
    int e = strip >> 3;
    int f = strip & 7;
    int m0 = m * 128;
    int ne = min(cnt[e], CAP);
    int nr = ne - m0;
    if (nr <= 0) return;
    if (nr > 128) nr = 128;
    int slot0 = e * CAP + m0;
    int fbase = f * 128;

    __shared__ __align__(16) unsigned char Asm[128 * PITCH];
    __shared__ __align__(16) unsigned char Bgm[128 * PITCH];
    __shared__ __align__(16) unsigned char Bum[128 * PITCH];

    int tid = threadIdx.x;
    // A staging: row ar, chunk pair (8 bf16 each)
    int ar = tid & 127;
    int ac0 = (tid >> 7) * 2;
    int atok = rowtok[slot0 + min(ar, nr - 1)];
    const uint4* agp = (const uint4*)(xb + (size_t)atok * D_DIM) + ac0;
    uint4* alp = (uint4*)(Asm + ar * PITCH + ac0 * 16);
    // B staging: col bf, k-group bkg (16 rows)
    int bf = tid & 127;
    int bkg = tid >> 7;
    size_t wbase = (size_t)e * ((size_t)D_DIM * F_DIM) + (size_t)(bkg * 16) * F_DIM
                 + (size_t)fbase + bf;
    const float* gp = wg + wbase;
    const float* up = wu + wbase;
    uint4* blg = (uint4*)(Bgm + bf * PITCH + bkg * 32);
    uint4* blu = (uint4*)(Bum + bf * PITCH + bkg * 32);

    int l = tid & 63, wid = tid >> 6;
    int wr = wid >> 2, wc = wid & 3;
    int ln = l & 15, lq = l >> 4;
    const unsigned char* Ab = Asm + (wr * 64 + ln) * PITCH + lq * 16;
    const unsigned char* Bgb = Bgm + (wc * 32 + ln) * PITCH + lq * 16;
    const unsigned char* Bub = Bum + (wc * 32 + ln) * PITCH + lq * 16;

    f32x4 accg[4][2], accu[4][2];
    #pragma unroll
    for (int mi = 0; mi < 4; ++mi)
        #pragma unroll
        for (int ni = 0; ni < 2; ++ni) {
            accg[mi][ni] = (f32x4){0.f, 0.f, 0.f, 0.f};
            accu[mi][ni] = (f32x4){0.f, 0.f, 0.f, 0.f};
        }

    uint4 ra0, ra1;
    float rg[16], ru[16];
    // prologue: tile 0 loads
    ra0 = agp[0]; ra1 = agp[1];
    #pragma unroll
    for (int j = 0; j < 16; ++j) {
        rg[j] = gp[(size_t)j * F_DIM];
        ru[j] = up[(size_t)j * F_DIM];
    }

    const int NT = D_DIM / 64;
    for (int t = 0; t < NT; ++t) {
        __syncthreads();
        alp[0] = ra0; alp[1] = ra1;
        uint4 gv, uv;
        gv.x = pack2(rg[0], rg[1]);  gv.y = pack2(rg[2], rg[3]);
        gv.z = pack2(rg[4], rg[5]);  gv.w = pack2(rg[6], rg[7]);
        blg[0] = gv;
        gv.x = pack2(rg[8], rg[9]);  gv.y = pack2(rg[10], rg[11]);
        gv.z = pack2(rg[12], rg[13]); gv.w = pack2(rg[14], rg[15]);
        blg[1] = gv;
        uv.x = pack2(ru[0], ru[1]);  uv.y = pack2(ru[2], ru[3]);
        uv.z = pack2(ru[4], ru[5]);  uv.w = pack2(ru[6], ru[7]);
        blu[0] = uv;
        uv.x = pack2(ru[8], ru[9]);  uv.y = pack2(ru[10], ru[11]);
        uv.z = pack2(ru[12], ru[13]); uv.w = pack2(ru[14], ru[15]);
        blu[1] = uv;
        __syncthreads();
        if (t + 1 < NT) {
            ra0 = agp[(t + 1) * 8];
            ra1 = agp[(t + 1) * 8 + 1];
            size_t ko = (size_t)(t + 1) * 64 * F_DIM;
            #pragma unroll
            for (int j = 0; j < 16; ++j) {
                rg[j] = gp[ko + (size_t)j * F_DIM];
                ru[j] = up[ko + (size_t)j * F_DIM];
            }
        }
        #pragma unroll
        for (int kk = 0; kk < 2; ++kk) {
            short8 af[4];
            #pragma unroll
            for (int mi = 0; mi < 4; ++mi)
                af[mi] = *(const short8*)(Ab + mi * 16 * PITCH + kk * 64);
            short8 bgf[2], buf_[2];
            #pragma unroll
            for (int ni = 0; ni < 2; ++ni) {
                bgf[ni]  = *(const short8*)(Bgb + ni * 16 * PITCH + kk * 64);
                buf_[ni] = *(const short8*)(Bub + ni * 16 * PITCH + kk * 64);
            }
            #pragma unroll
            for (int mi = 0; mi < 4; ++mi)
                #pragma unroll
                for (int ni = 0; ni < 2; ++ni) {
                    accg[mi][ni] = __builtin_amdgcn_mfma_f32_16x16x32_bf16(af[mi], bgf[ni],  accg[mi][ni], 0, 0, 0);
                    accu[mi][ni] = __builtin_amdgcn_mfma_f32_16x16x32_bf16(af[mi], buf_[ni], accu[mi][ni], 0, 0, 0);
                }
        }
    }

    #pragma unroll
    for (int mi = 0; mi < 4; ++mi) {
        int rbase = wr * 64 + mi * 16 + lq * 4;
        #pragma unroll
        for (int j = 0; j < 4; ++j) {
            int row = rbase + j;
            if (row < nr) {
                size_t hb = (size_t)(slot0 + row) * F_DIM + (size_t)fbase + wc * 32 + ln;
                #pragma unroll
                for (int ni = 0; ni < 2; ++ni) {
                    float g = accg[mi][ni][j], u = accu[mi][ni][j];
                    float hv = g / (1.f + __expf(-g)) * u;
                    h[hb + ni * 16] = f_to_bf16(hv);
                }
            }
        }
    }
}

// ------- Down GEMM + combine: 128m x 128d tile, BK=64, 512 thr -------
__global__ __launch_bounds__(512, 4) void down_k(const uint16_t* __restrict__ h,
        const float* __restrict__ wd, const int* __restrict__ cnt,
        const int* __restrict__ rowtok, const float* __restrict__ aw,
        float* __restrict__ out) {
    int flat = blockIdx.x;
    int xcd = flat & 7;
    int idx = flat >> 3;
    int m = idx & 7;
    int sloc = idx >> 3;
    int strip = sloc * 8 + xcd;          // 0..1023 = e*16 + f
    int e = strip >> 4;
    int f = strip & 15;
    int m0 = m * 128;
    int ne = min(cnt[e], CAP);
    int nr = ne - m0;
    if (nr <= 0) return;
    if (nr > 128) nr = 128;
    int slot0 = e * CAP + m0;
    int fbase = f * 128;

    __shared__ __align__(16) unsigned char Asm[128 * PITCH];
    __shared__ __align__(16) unsigned char Bsm[128 * PITCH];

    int tid = threadIdx.x;
    int ar = tid & 127;
    int ac0 = (tid >> 7) * 2;
    const uint4* agp = (const uint4*)(h + (size_t)(slot0 + min(ar, nr - 1)) * F_DIM) + ac0;
    uint4* alp = (uint4*)(Asm + ar * PITCH + ac0 * 16);

    int bf = tid & 127;
    int bkg = tid >> 7;
    const float* bp = wd + (size_t)e * ((size_t)F_DIM * D_DIM) + (size_t)(bkg * 16) * D_DIM
                    + (size_t)fbase + bf;
    uint4* blp = (uint4*)(Bsm + bf * PITCH + bkg * 32);

    int l = tid & 63, wid = tid >> 6;
    int wr = wid >> 2, wc = wid & 3;
    int ln = l & 15, lq = l >> 4;
    const unsigned char* Ab = Asm + (wr * 64 + ln) * PITCH + lq * 16;
    const unsigned char* Bb = Bsm + (wc * 32 + ln) * PITCH + lq * 16;

    f32x4 acc[4][2];
    #pragma unroll
    for (int mi = 0; mi < 4; ++mi)
        #pragma unroll
        for (int ni = 0; ni < 2; ++ni)
            acc[mi][ni] = (f32x4){0.f, 0.f, 0.f, 0.f};

    uint4 ra0, ra1;
    float rb[16];
    ra0 = agp[0]; ra1 = agp[1];
    #pragma unroll
    for (int j = 0; j < 16; ++j) rb[j] = bp[(size_t)j * D_DIM];

    const int NT = F_DIM / 64;
    for (int t = 0; t < NT; ++t) {
        __syncthreads();
        alp[0] = ra0; alp[1] = ra1;
        uint4 bv;
        bv.x = pack2(rb[0], rb[1]);  bv.y = pack2(rb[2], rb[3]);
        bv.z = pack2(rb[4], rb[5]);  bv.w = pack2(rb[6], rb[7]);
        blp[0] = bv;
        bv.x = pack2(rb[8], rb[9]);  bv.y = pack2(rb[10], rb[11]);
        bv.z = pack2(rb[12], rb[13]); bv.w = pack2(rb[14], rb[15]);
        blp[1] = bv;
        __syncthreads();
        if (t + 1 < NT) {
            ra0 = agp[(t + 1) * 8];
            ra1 = agp[(t + 1) * 8 + 1];
            size_t ko = (size_t)(t + 1) * 64 * D_DIM;
            #pragma unroll
            for (int j = 0; j < 16; ++j) rb[j] = bp[ko + (size_t)j * D_DIM];
        }
        #pragma unroll
        for (int kk = 0; kk < 2; ++kk) {
            short8 af[4];
            #pragma unroll
            for (int mi = 0; mi < 4; ++mi)
                af[mi] = *(const short8*)(Ab + mi * 16 * PITCH + kk * 64);
            short8 bf2[2];
            #pragma unroll
            for (int ni = 0; ni < 2; ++ni)
                bf2[ni] = *(const short8*)(Bb + ni * 16 * PITCH + kk * 64);
            #pragma unroll
            for (int mi = 0; mi < 4; ++mi)
                #pragma unroll
                for (int ni = 0; ni < 2; ++ni)
                    acc[mi][ni] = __builtin_amdgcn_mfma_f32_16x16x32_bf16(af[mi], bf2[ni], acc[mi][ni], 0, 0, 0);
        }
    }

    #pragma unroll
    for (int mi = 0; mi < 4; ++mi) {
        int rbase = wr * 64 + mi * 16 + lq * 4;
        #pragma unroll
        for (int j = 0; j < 4; ++j) {
            int row = rbase + j;
            if (row < nr) {
                int slot = slot0 + row;
                int tok = rowtok[slot];
                float wgt = aw[slot];
                float* orow = out + (size_t)tok * D_DIM + (size_t)fbase + wc * 32 + ln;
                #pragma unroll
                for (int ni = 0; ni < 2; ++ni)
                    atomicAdd(&orow[ni * 16], acc[mi][ni][j] * wgt);
            }
        }
    }
}

extern "C" void kernel_launch(void* const* d_in, const int* in_sizes, int n_in,
                              void* d_out, int out_size, void* d_ws, size_t ws_size,
                              hipStream_t stream) {
    const float* x  = (const float*)d_in[0];
    const float* gw = (const float*)d_in[1];
    const float* wg = (const float*)d_in[2];
    const float* wu = (const float*)d_in[3];
    const float* wd = (const float*)d_in[4];
    float* out = (float*)d_out;
    int T = in_sizes[0] / D_DIM;

    char* ws = (char*)d_ws;
    size_t off = 0;
    auto alloc = [&](size_t bytes) -> void* {
        void* p = ws + off;
        off = (off + bytes + 255) & ~(size_t)255;
        return p;
    };
    int*      cnt    = (int*)     alloc(E_NUM * sizeof(int));
    int*      topi   = (int*)     alloc((size_t)T * K_TOP * sizeof(int));
    float*    topw   = (float*)   alloc((size_t)T * K_TOP * sizeof(float));
    int*      rowtok = (int*)     alloc((size_t)E_NUM * CAP * sizeof(int));
    float*    aw     = (float*)   alloc((size_t)E_NUM * CAP * sizeof(float));
    uint16_t* xb     = (uint16_t*)alloc((size_t)T * D_DIM * sizeof(uint16_t));
    uint16_t* h      = (uint16_t*)alloc((size_t)E_NUM * CAP * F_DIM * sizeof(uint16_t));

    hipMemsetAsync(cnt, 0, E_NUM * sizeof(int), stream);
    hipMemsetAsync(out, 0, (size_t)out_size * sizeof(float), stream);

    int n8 = T * D_DIM / 8;
    cvtx_k<<<(n8 + 255) / 256, 256, 0, stream>>>(x, xb, n8);
    router_k<<<T, 64, 0, stream>>>(x, gw, topi, topw);
    assign_k<<<(T + 255) / 256, 256, 0, stream>>>(topi, topw, cnt, rowtok, aw, T);
    gateup_k<<<E_NUM * 8 * 8, 512, 0, stream>>>(xb, wg, wu, cnt, rowtok, h);
    down_k<<<E_NUM * 16 * 8, 512, 0, stream>>>(h, wd, cnt, rowtok, aw, out);
}